// Round 5
// baseline (632.201 us; speedup 1.0000x reference)
//
#include <hip/hip_runtime.h>
#include <hip/hip_bf16.h>
#include <stdint.h>

// Problem constants (B=4, T=2048, D=256, M=128, L=16, P=2048)
#define TAU 0.35f   // bf16-path score uncertainty window for fp32 refinement

typedef __attribute__((ext_vector_type(8))) short bf16x8;
typedef __attribute__((ext_vector_type(4))) float f32x4;

__device__ __forceinline__ unsigned short f2bf(float f) {
  __bf16 h = (__bf16)f;
  return __builtin_bit_cast(unsigned short, h);
}
__device__ __forceinline__ float bf2f(unsigned short u) {
  unsigned int v = ((unsigned int)u) << 16;
  return __builtin_bit_cast(float, v);
}
__device__ __forceinline__ void async_copy16(const void* g, void* l) {
  __builtin_amdgcn_global_load_lds(
      (const __attribute__((address_space(1))) unsigned int*)g,
      (__attribute__((address_space(3))) unsigned int*)l, 16, 0, 0);
}

// ---------------------------------------------------------------------------
// K0: x -> xt2[b][kc][k8][d][8] (bf16, k-slice-major: t = kc*64 + k8*8 + ke).
//     Also: w1 -> w1t[n][k]; logits init; njobs[0..3] zero (per-batch buckets).
// ---------------------------------------------------------------------------
__global__ __launch_bounds__(256) void k_prep(
    const float* __restrict__ x, const float* __restrict__ w1,
    const float* __restrict__ b2,
    unsigned short* __restrict__ xt, unsigned short* __restrict__ w1t,
    float* __restrict__ logits, int* __restrict__ njobs) {
  __shared__ float tileS[64][65];
  __shared__ float tx[64][132];
  int bx = blockIdx.x, tid = threadIdx.x;
  if (bx == 0 && tid < 4) njobs[tid] = 0;
  if (bx < 64) {  // logits init: 16384 floats
    int i = bx * 256 + tid;
    logits[i] = b2[i & 1];
  }
  if (bx < 256) {  // x-part: 64 t-rows x 128 d-cols per block
    int b = bx >> 6, kc = (bx >> 1) & 31, dh = bx & 1;
    const float* src = x + ((size_t)b * 2048 + (size_t)kc * 64) * 256 + dh * 128;
#pragma unroll
    for (int p = 0; p < 8; ++p) {
      int idx = p * 256 + tid;
      int row = idx >> 5, f4 = idx & 31;   // row 0..63, f4 0..31 (128 floats)
      *(float4*)&tx[row][f4 * 4] = *(const float4*)&src[(size_t)row * 256 + f4 * 4];
    }
    __syncthreads();
    unsigned short* dst = xt + ((size_t)(b * 32 + kc)) * 16384 + dh * 1024;
#pragma unroll
    for (int p = 0; p < 4; ++p) {
      int idx = p * 256 + tid;
      int d0 = idx & 127, k8 = idx >> 7;   // d0 0..127, k8 0..7
      bf16x8 v;
#pragma unroll
      for (int j = 0; j < 8; ++j) v[j] = (short)f2bf(tx[k8 * 8 + j][d0]);
      *(bf16x8*)&dst[(size_t)k8 * 2048 + d0 * 8] = v;
    }
  } else {  // w1 tiles: k-tiles(12) * n-tiles(4)  (unchanged layout)
    int wt = bx - 256;
    int k6 = wt >> 2, n6 = wt & 3;
    int j = tid & 63, i0 = tid >> 6;
    const float* src = w1 + ((size_t)k6 * 64) * 256 + n6 * 64;
    for (int i = i0; i < 64; i += 4) tileS[i][j] = src[(size_t)i * 256 + j];
    __syncthreads();
    unsigned short* dst = w1t + ((size_t)n6 * 64) * 768 + k6 * 64;
    for (int r = i0; r < 64; r += 4) dst[(size_t)r * 768 + j] = f2bf(tileS[j][r]);
  }
}

// ---------------------------------------------------------------------------
// K1 v4 (unchanged from round 4): fetch-once, 2 blocks/CU, linear B layout.
// ---------------------------------------------------------------------------
__global__ __launch_bounds__(512, 4) void k_gemm_rep(
    const float* __restrict__ head, const float* __restrict__ tail,
    const unsigned short* __restrict__ xt,
    float* __restrict__ hrep, float* __restrict__ trep) {
  __shared__ unsigned short As[2][2048];   // [k8 0..7][row 0..31][8]
  __shared__ unsigned short Bs[2][16384];  // [k8 0..7][col 0..255][8]
  int bx = blockIdx.x;
  int b = bx >> 7, mt = bx & 127;   // mt<64: head rowtile, else tail
  const float* Asrc = ((mt < 64) ? head : tail) +
                      ((size_t)(b * 2048 + (mt & 63) * 32)) * 2048;
  float* Crep = (mt < 64) ? hrep : trep;
  const unsigned short* Bsrc = xt + (size_t)b * 524288;

  int tid = threadIdx.x, lane = tid & 63, w = tid >> 6;
  int rg = w & 1, cg = w >> 1;
  int l4 = lane >> 4, l15 = lane & 15;

  int arow = tid >> 3, ak8 = tid & 7;
  const float* aptr = Asrc + (size_t)arow * 2048 + ak8 * 8;
  int awi = (ak8 * 32 + arow) * 8;

  const unsigned short* bg = Bsrc + tid * 8;

  int aoff[2];
  int boff[2][4];
#pragma unroll
  for (int kh = 0; kh < 2; ++kh) {
    aoff[kh] = ((kh * 4 + l4) * 32 + rg * 16 + l15) * 8;
#pragma unroll
    for (int ct = 0; ct < 4; ++ct)
      boff[kh][ct] = ((kh * 4 + l4) * 256 + cg * 64 + ct * 16 + l15) * 8;
  }

  f32x4 acc[4];
#pragma unroll
  for (int ct = 0; ct < 4; ++ct) acc[ct] = (f32x4){0.f, 0.f, 0.f, 0.f};

  float4 av0, av1;
  auto STAGEB = [&](int buf) {
#pragma unroll
    for (int a = 0; a < 4; ++a)
      async_copy16(bg + (size_t)a * 4096, &Bs[buf][(tid + a * 512) * 8]);
    bg += 16384;
  };
  auto LOADA = [&]() {
    const float4* ap = (const float4*)aptr;
    av0 = ap[0]; av1 = ap[1];
    aptr += 64;
  };
  auto WRITEA = [&](int buf) {
    bf16x8 p;
    p[0] = (short)f2bf(av0.x); p[1] = (short)f2bf(av0.y);
    p[2] = (short)f2bf(av0.z); p[3] = (short)f2bf(av0.w);
    p[4] = (short)f2bf(av1.x); p[5] = (short)f2bf(av1.y);
    p[6] = (short)f2bf(av1.z); p[7] = (short)f2bf(av1.w);
    *(bf16x8*)&As[buf][awi] = p;
  };
  auto MMA = [&](int buf) {
    const unsigned short* A_ = As[buf];
    const unsigned short* B_ = Bs[buf];
#pragma unroll
    for (int kh = 0; kh < 2; ++kh) {
      bf16x8 a0 = *(const bf16x8*)&A_[aoff[kh]];
#pragma unroll
      for (int ct = 0; ct < 4; ++ct) {
        bf16x8 bb = *(const bf16x8*)&B_[boff[kh][ct]];
        acc[ct] = __builtin_amdgcn_mfma_f32_16x16x32_bf16(a0, bb, acc[ct], 0, 0, 0);
      }
    }
  };

  STAGEB(0);
  if (tid < 256) { LOADA(); WRITEA(0); }
  __syncthreads();

  for (int it = 0; it < 32; ++it) {
    int cur = it & 1, nxt = cur ^ 1;
    if (it < 31) {
      STAGEB(nxt);
      if (tid < 256) LOADA();
    }
    MMA(cur);
    if (it < 31 && tid < 256) WRITEA(nxt);
    __syncthreads();
  }

  size_t prow = (size_t)b * 2048 + (size_t)(mt & 63) * 32 + rg * 16 + (l4 << 2);
  int cb = cg * 64 + l15;
#pragma unroll
  for (int ct = 0; ct < 4; ++ct)
#pragma unroll
    for (int i = 0; i < 4; ++i)
      Crep[(prow + i) * 256 + cb + ct * 16] = acc[ct][i];
}

// ---------------------------------------------------------------------------
// K2pre: featbf[p][0:256]=h, [256:512]=t, [512:768]=h*t  (bf16)
// ---------------------------------------------------------------------------
__global__ __launch_bounds__(256) void k_feat(
    const float* __restrict__ hrep, const float* __restrict__ trep,
    unsigned short* __restrict__ featbf) {
  int gid = blockIdx.x * 256 + threadIdx.x;
  int p = gid >> 6, d0 = (gid & 63) * 4;
  float4 h4 = *(const float4*)&hrep[(size_t)p * 256 + d0];
  float4 t4 = *(const float4*)&trep[(size_t)p * 256 + d0];
  ushort4 a, bb, c;
  a.x = f2bf(h4.x); a.y = f2bf(h4.y); a.z = f2bf(h4.z); a.w = f2bf(h4.w);
  bb.x = f2bf(t4.x); bb.y = f2bf(t4.y); bb.z = f2bf(t4.z); bb.w = f2bf(t4.w);
  c.x = f2bf(h4.x * t4.x); c.y = f2bf(h4.y * t4.y);
  c.z = f2bf(h4.z * t4.z); c.w = f2bf(h4.w * t4.w);
  *(ushort4*)&featbf[(size_t)p * 768 + d0] = a;
  *(ushort4*)&featbf[(size_t)p * 768 + 256 + d0] = bb;
  *(ushort4*)&featbf[(size_t)p * 768 + 512 + d0] = c;
}

// ---------------------------------------------------------------------------
// K2: relu(feat @ w1 + b1) @ w2 + b2 -> logits (unchanged)
// ---------------------------------------------------------------------------
__global__ __launch_bounds__(256, 4) void k_gemm_mlp(
    const unsigned short* __restrict__ featb, const unsigned short* __restrict__ w1t,
    const float* __restrict__ b1, const float* __restrict__ w2,
    float* __restrict__ logits) {
  __shared__ unsigned short As[2][4096], Bs[2][4096];
  int bx = blockIdx.x;
  int ntile = bx >> 7;   // 0..3
  int mtile = bx & 127;  // 0..127
  int tid = threadIdx.x, lane = tid & 63, w = tid >> 6;

  const unsigned short* ag[2];
  const unsigned short* bgp[2];
  int dofs[2];
#pragma unroll
  for (int a = 0; a < 2; ++a) {
    int rowofs = a * 8 + (lane >> 3);
    int k8 = (lane & 7) ^ (rowofs & 7);
    ag[a] = featb + (size_t)(mtile * 64 + w * 16 + rowofs) * 768 + k8 * 8;
    bgp[a] = w1t + (size_t)(ntile * 64 + w * 16 + rowofs) * 768 + k8 * 8;
    dofs[a] = (w * 128 + a * 64 + lane) * 8;
  }
  int sw0 = (lane >> 4) ^ (lane & 7);
  int sw1 = (4 + (lane >> 4)) ^ (lane & 7);
  int arowc = (w * 16 + (lane & 15)) * 8;
  int colc[4];
#pragma unroll
  for (int ct = 0; ct < 4; ++ct) colc[ct] = (ct * 16 + (lane & 15)) * 8;

  f32x4 acc[4];
#pragma unroll
  for (int ct = 0; ct < 4; ++ct) acc[ct] = (f32x4){0.f, 0.f, 0.f, 0.f};

#pragma unroll
  for (int a = 0; a < 2; ++a) {
    async_copy16(ag[a], &As[0][dofs[a]]); ag[a] += 64;
    async_copy16(bgp[a], &Bs[0][dofs[a]]); bgp[a] += 64;
  }
  __syncthreads();

  for (int it = 0; it < 12; ++it) {
    int cur = it & 1, nxt = cur ^ 1;
    if (it < 11) {
#pragma unroll
      for (int a = 0; a < 2; ++a) {
        async_copy16(ag[a], &As[nxt][dofs[a]]); ag[a] += 64;
        async_copy16(bgp[a], &Bs[nxt][dofs[a]]); bgp[a] += 64;
      }
    }
    const unsigned short* A_ = As[cur];
    const unsigned short* B_ = Bs[cur];
    bf16x8 a0 = *(const bf16x8*)&A_[(arowc + sw0) * 8];
    bf16x8 a1 = *(const bf16x8*)&A_[(arowc + sw1) * 8];
#pragma unroll
    for (int ct = 0; ct < 4; ++ct) {
      bf16x8 b0 = *(const bf16x8*)&B_[(colc[ct] + sw0) * 8];
      acc[ct] = __builtin_amdgcn_mfma_f32_16x16x32_bf16(a0, b0, acc[ct], 0, 0, 0);
    }
#pragma unroll
    for (int ct = 0; ct < 4; ++ct) {
      bf16x8 b1 = *(const bf16x8*)&B_[(colc[ct] + sw1) * 8];
      acc[ct] = __builtin_amdgcn_mfma_f32_16x16x32_bf16(a1, b1, acc[ct], 0, 0, 0);
    }
    __syncthreads();
  }

  float bv[4], w20[4], w21[4];
#pragma unroll
  for (int ct = 0; ct < 4; ++ct) {
    int col = ntile * 64 + ct * 16 + (lane & 15);
    bv[ct] = b1[col]; w20[ct] = w2[col * 2]; w21[ct] = w2[col * 2 + 1];
  }
#pragma unroll
  for (int i = 0; i < 4; ++i) {
    float s0 = 0.f, s1 = 0.f;
#pragma unroll
    for (int ct = 0; ct < 4; ++ct) {
      float r = fmaxf(acc[ct][i] + bv[ct], 0.f);
      s0 += r * w20[ct]; s1 += r * w21[ct];
    }
#pragma unroll
    for (int off = 1; off < 16; off <<= 1) {
      s0 += __shfl_xor(s0, off); s1 += __shfl_xor(s1, off);
    }
    if ((lane & 15) == 0) {
      int row = mtile * 64 + w * 16 + ((lane >> 4) << 2) + i;
      atomicAdd(&logits[row * 2], s0);
      atomicAdd(&logits[row * 2 + 1], s1);
    }
  }
}

// ---------------------------------------------------------------------------
// K3b: per-mention top-1 + uncertainty set; emit refine jobs BUCKETED BY b
// (so k_refine can batch same-b jobs against one shared x[b] pass).
// ---------------------------------------------------------------------------
__global__ void k_select(const float* __restrict__ logits, int* __restrict__ idxv,
                         float* __restrict__ mval, int* __restrict__ cmask,
                         int* __restrict__ njobs, int* __restrict__ jobs) {
  int q = blockIdx.x * 256 + threadIdx.x;
  if (q >= 512) return;
  int base = q * 16;
  float s[16];
#pragma unroll
  for (int i = 0; i < 16; ++i) s[i] = logits[(size_t)(base + i) * 2 + 1];
  float best = s[0]; int bi = 0;
#pragma unroll
  for (int i = 1; i < 16; ++i) if (s[i] > best) { best = s[i]; bi = i; }
  int mask = 0, cnt = 0;
#pragma unroll
  for (int i = 0; i < 16; ++i) if (s[i] > best - TAU) { mask |= 1 << i; ++cnt; }
  idxv[q] = bi; mval[q] = best;
  if (cnt > 1) {
    cmask[q] = mask;
    int bb = q >> 7;   // batch index (code>>11 == q>>7)
    for (int i = 0; i < 16; ++i)
      if ((mask >> i) & 1) {
        int j = atomicAdd(&njobs[bb], 1);
        jobs[bb * 2048 + j] = base + i;
      }
  } else cmask[q] = 0;
}

// ---------------------------------------------------------------------------
// K3c v2: fp32 exact score recompute, JPB=4 jobs per group (same batch b).
//  - 4 jobs' head+tail rows staged INTERLEAVED: rows4[t][8] -> the per-t
//    values for all 4 jobs arrive in 2 uniform ds_read_b128 broadcasts.
//  - x read once per group as float2 (8B/lane); each x element feeds 16 FMA
//    (was 2) -> x traffic /4 and unroll-8 covers load latency.
//  - w1 pass batched identically via feat4[ii][j] (1 b128 + 4 FMA / elem).
// LDS ~140KB -> 1 block/CU; grid 256 grid-strides over job groups per b.
// ---------------------------------------------------------------------------
#define JPB 4
__global__ __launch_bounds__(1024) void k_refine(
    const int* __restrict__ njobs, const int* __restrict__ jobs,
    const float* __restrict__ head, const float* __restrict__ tail,
    const float* __restrict__ x, const float* __restrict__ w1,
    const float* __restrict__ b1, const float* __restrict__ w2,
    const float* __restrict__ b2, float* __restrict__ refined) {
  __shared__ float rows4[2048][8];    // 64KB [t][j]: j<4 head, j>=4 tail
  __shared__ float redH[8][4][256];   // 32KB [tseg][j][d] (reused for hidden)
  __shared__ float redT[8][4][256];   // 32KB
  __shared__ float feat4[768][4];     // 12KB [ii][j]
  __shared__ float part[4][4];
  __shared__ int scode[4];
  int tid = threadIdx.x;
  int tseg = tid >> 7, dp = tid & 127;   // main loop: 8 t-segs x 128 d-pairs
  int hseg = tid >> 8, d = tid & 255;    // MLP: 4 ii-segs x 256 d

  for (int b = 0; b < 4; ++b) {
    int nj = njobs[b];
    int ng = (nj + JPB - 1) / JPB;
    const float* xb = x + (size_t)b * 2048 * 256;
    for (int grp = blockIdx.x; grp < ng; grp += gridDim.x) {
      if (tid < 4) scode[tid] = jobs[b * 2048 + min(grp * JPB + tid, nj - 1)];
      __syncthreads();
      // ---- stage rows interleaved; LDS writes linear (conflict-free) ----
#pragma unroll
      for (int r = 0; r < 16; ++r) {
        int idx = r * 1024 + tid;
        int t = idx >> 3, j = idx & 7;
        int p = scode[j & 3] & 2047;
        const float* src = (j < 4) ? head : tail;
        ((float*)rows4)[idx] = src[((size_t)(b * 2048 + p)) * 2048 + t];
      }
      __syncthreads();
      // ---- main dot: hr/tr[j] over this thread's 256 t's, 2 d's ----
      float2 hr[4], tr[4];
#pragma unroll
      for (int j = 0; j < 4; ++j) { hr[j] = {0.f, 0.f}; tr[j] = {0.f, 0.f}; }
      const float* xp = xb + (size_t)(tseg * 256) * 256 + dp * 2;
#pragma unroll 8
      for (int t = 0; t < 256; ++t) {
        float2 xv = *(const float2*)(xp + (size_t)t * 256);
        float4 hv = *(const float4*)&rows4[tseg * 256 + t][0];
        float4 tv = *(const float4*)&rows4[tseg * 256 + t][4];
        hr[0].x += hv.x * xv.x; hr[0].y += hv.x * xv.y;
        hr[1].x += hv.y * xv.x; hr[1].y += hv.y * xv.y;
        hr[2].x += hv.z * xv.x; hr[2].y += hv.z * xv.y;
        hr[3].x += hv.w * xv.x; hr[3].y += hv.w * xv.y;
        tr[0].x += tv.x * xv.x; tr[0].y += tv.x * xv.y;
        tr[1].x += tv.y * xv.x; tr[1].y += tv.y * xv.y;
        tr[2].x += tv.z * xv.x; tr[2].y += tv.z * xv.y;
        tr[3].x += tv.w * xv.x; tr[3].y += tv.w * xv.y;
      }
#pragma unroll
      for (int j = 0; j < 4; ++j) {
        *(float2*)&redH[tseg][j][dp * 2] = hr[j];
        *(float2*)&redT[tseg][j][dp * 2] = tr[j];
      }
      __syncthreads();
      // ---- feat: combine 8 t-segs ----
      if (tid < 256) {
#pragma unroll
        for (int j = 0; j < 4; ++j) {
          float fh = 0.f, ft = 0.f;
#pragma unroll
          for (int s = 0; s < 8; ++s) { fh += redH[s][j][tid]; ft += redT[s][j][tid]; }
          feat4[tid][j] = fh; feat4[256 + tid][j] = ft; feat4[512 + tid][j] = fh * ft;
        }
      }
      __syncthreads();
      // ---- hidden: hp[j][d] over 192 ii per seg; w1 read once per group ----
      float hp[4] = {0.f, 0.f, 0.f, 0.f};
      const float* w1c = w1 + (size_t)(hseg * 192) * 256 + d;
#pragma unroll 4
      for (int ii = 0; ii < 192; ++ii) {
        float wv = w1c[(size_t)ii * 256];
        float4 fv = *(const float4*)&feat4[hseg * 192 + ii][0];
        hp[0] += fv.x * wv; hp[1] += fv.y * wv; hp[2] += fv.z * wv; hp[3] += fv.w * wv;
      }
#pragma unroll
      for (int j = 0; j < 4; ++j) redH[hseg][j][d] = hp[j];
      __syncthreads();
      // ---- finish: relu(+b1) * w2[:,1], reduce over d ----
      if (tid < 256) {
        float w2v = w2[tid * 2 + 1];
        float b1v = b1[tid];
#pragma unroll
        for (int j = 0; j < 4; ++j) {
          float h = b1v + redH[0][j][tid] + redH[1][j][tid] + redH[2][j][tid] + redH[3][j][tid];
          h = fmaxf(h, 0.f) * w2v;
#pragma unroll
          for (int off = 1; off < 64; off <<= 1) h += __shfl_xor(h, off);
          if ((tid & 63) == 0) part[j][tid >> 6] = h;
        }
      }
      __syncthreads();
      if (tid < 4)
        refined[scode[tid]] = part[tid][0] + part[tid][1] + part[tid][2] + part[tid][3] + b2[1];
      __syncthreads();
    }
  }
}

// ---------------------------------------------------------------------------
// K4a: rep_m[q][d] = tail_rep[q*16+argmax][d] * max_val
// ---------------------------------------------------------------------------
__global__ __launch_bounds__(256) void k_repm(
    const int* __restrict__ idxv, const float* __restrict__ mval,
    const int* __restrict__ cmask, const float* __restrict__ refined,
    const float* __restrict__ trep, float* __restrict__ repm) {
  int q = blockIdx.x, d = threadIdx.x;
  int mask = cmask[q]; int bi; float v;
  if (mask) {
    bi = -1; v = -1e30f;
    for (int i = 0; i < 16; ++i)
      if ((mask >> i) & 1) { float s = refined[q * 16 + i]; if (s > v) { v = s; bi = i; } }
  } else { bi = idxv[q]; v = mval[q]; }
  repm[(size_t)q * 256 + d] = trep[((size_t)q * 16 + bi) * 256 + d] * v;
}

// ---------------------------------------------------------------------------
// K4b: out[b][t][d] = x + sum_m cmp[b][m][t] * rep_m[b][m][d]  (512 blocks)
// ---------------------------------------------------------------------------
__global__ __launch_bounds__(256) void k_merge(
    const float* __restrict__ cmp, const float* __restrict__ repm,
    const float* __restrict__ x, float* __restrict__ out) {
  __shared__ float cl[128 * 16];
  int bx = blockIdx.x, b = bx >> 7, t0 = (bx & 127) * 16;
  int tid = threadIdx.x;
#pragma unroll
  for (int it = 0; it < 2; ++it) {
    int f = it * 256 + tid;
    int row = f >> 2, c4 = (f & 3) * 4;
    *(float4*)&cl[row * 16 + c4] =
        *(const float4*)&cmp[((size_t)(b * 128 + row)) * 2048 + t0 + c4];
  }
  __syncthreads();
  float acc[16];
#pragma unroll
  for (int i = 0; i < 16; ++i) acc[i] = 0.f;
  int d = tid;
  for (int m = 0; m < 128; ++m) {
    float rv = repm[(size_t)(b * 128 + m) * 256 + d];
    const float4* c4p = (const float4*)&cl[m * 16];
#pragma unroll
    for (int jj = 0; jj < 4; ++jj) {
      float4 c = c4p[jj];
      acc[jj * 4] += c.x * rv; acc[jj * 4 + 1] += c.y * rv;
      acc[jj * 4 + 2] += c.z * rv; acc[jj * 4 + 3] += c.w * rv;
    }
  }
  const float* xb = x + ((size_t)(b * 2048 + t0)) * 256 + d;
  float* ob = out + ((size_t)(b * 2048 + t0)) * 256 + d;
#pragma unroll
  for (int tt = 0; tt < 16; ++tt) ob[(size_t)tt * 256] = xb[(size_t)tt * 256] + acc[tt];
}

// ---------------------------------------------------------------------------
// K5: masked KLDiv mean loss (single block)
// ---------------------------------------------------------------------------
__global__ __launch_bounds__(1024) void k_loss(
    const float* __restrict__ logits, const float* __restrict__ lab,
    const unsigned char* __restrict__ mask, float* __restrict__ out_loss) {
  __shared__ float rs[1024], rc[1024];
  int tid = threadIdx.x;
  float sum = 0.f, cnt = 0.f;
  for (int p = tid; p < 8192; p += 1024) {
    float l0 = logits[(size_t)p * 2], l1 = logits[(size_t)p * 2 + 1];
    float a0 = lab[(size_t)p * 2], a1 = lab[(size_t)p * 2 + 1];
    float mx = fmaxf(l0, l1);
    float lse = mx + logf(expf(l0 - mx) + expf(l1 - mx));
    float pw = 0.f;
    if (a0 > 0.f) pw += a0 * logf(fmaxf(a0, 1e-38f));
    if (a1 > 0.f) pw += a1 * logf(fmaxf(a1, 1e-38f));
    pw -= a0 * (l0 - lse) + a1 * (l1 - lse);
    if (mask[p]) { sum += pw; cnt += 1.f; }
  }
  rs[tid] = sum; rc[tid] = cnt;
  __syncthreads();
  for (int s = 512; s > 0; s >>= 1) {
    if (tid < s) { rs[tid] += rs[tid + s]; rc[tid] += rc[tid + s]; }
    __syncthreads();
  }
  if (tid == 0) *out_loss = rs[0] / (rc[0] * 2.0f);
}

// ---------------------------------------------------------------------------
extern "C" void kernel_launch(void* const* d_in, const int* in_sizes, int n_in,
                              void* d_out, int out_size, void* d_ws, size_t ws_size,
                              hipStream_t stream) {
  (void)in_sizes; (void)n_in; (void)out_size; (void)ws_size;
  const float* head = (const float*)d_in[0];
  const float* tail = (const float*)d_in[1];
  // d_in[2] = lens (uniform L=16) -- unused
  const float* x = (const float*)d_in[3];
  const float* cmp = (const float*)d_in[4];
  const float* lab = (const float*)d_in[5];
  const unsigned char* lmask = (const unsigned char*)d_in[6];
  const float* w1 = (const float*)d_in[7];
  const float* b1 = (const float*)d_in[8];
  const float* w2 = (const float*)d_in[9];
  const float* b2 = (const float*)d_in[10];
  float* out = (float*)d_out;

  char* ws = (char*)d_ws;
  size_t off = 0;
  auto alloc = [&](size_t bytes) -> void* {
    void* p = ws + off; off += (bytes + 255) & ~(size_t)255; return p;
  };
  unsigned short* xt = (unsigned short*)alloc(4ull * 256 * 2048 * 2);
  unsigned short* w1t = (unsigned short*)alloc(256ull * 768 * 2);
  float* hrep = (float*)alloc(8192ull * 256 * 4);
  float* trep = (float*)alloc(8192ull * 256 * 4);
  unsigned short* featb = (unsigned short*)alloc(8192ull * 768 * 2);
  float* logits = (float*)alloc(8192ull * 2 * 4);
  float* refined = (float*)alloc(8192ull * 4);
  int* idxv = (int*)alloc(512 * 4);
  float* mvalv = (float*)alloc(512 * 4);
  int* cmaskv = (int*)alloc(512 * 4);
  int* njobs = (int*)alloc(256);
  int* jobs = (int*)alloc(4 * 2048 * 4);
  float* repm = (float*)alloc(512ull * 256 * 4);

  k_prep<<<304, 256, 0, stream>>>(x, w1, b2, xt, w1t, logits, njobs);
  k_gemm_rep<<<512, 512, 0, stream>>>(head, tail, xt, hrep, trep);
  k_feat<<<2048, 256, 0, stream>>>(hrep, trep, featb);
  k_gemm_mlp<<<512, 256, 0, stream>>>(featb, w1t, b1, w2, logits);
  k_select<<<2, 256, 0, stream>>>(logits, idxv, mvalv, cmaskv, njobs, jobs);
  k_refine<<<256, 1024, 0, stream>>>(njobs, jobs, head, tail, x, w1, b1, w2, b2, refined);
  k_repm<<<512, 256, 0, stream>>>(idxv, mvalv, cmaskv, refined, trep, repm);
  k_merge<<<512, 256, 0, stream>>>(cmp, repm, x, out);
  k_loss<<<1, 1024, 0, stream>>>(logits, lab, lmask, out + 4ull * 2048 * 256);
}

// Round 6
// 320.781 us; speedup vs baseline: 1.9708x; 1.9708x over previous
//
#include <hip/hip_runtime.h>
#include <hip/hip_bf16.h>
#include <stdint.h>

// Problem constants (B=4, T=2048, D=256, M=128, L=16, P=2048)
#define TAU 0.35f   // bf16-path score uncertainty window for fp32 refinement

typedef __attribute__((ext_vector_type(8))) short bf16x8;
typedef __attribute__((ext_vector_type(4))) float f32x4;

__device__ __forceinline__ unsigned short f2bf(float f) {
  __bf16 h = (__bf16)f;
  return __builtin_bit_cast(unsigned short, h);
}
__device__ __forceinline__ float bf2f(unsigned short u) {
  unsigned int v = ((unsigned int)u) << 16;
  return __builtin_bit_cast(float, v);
}
__device__ __forceinline__ void async_copy16(const void* g, void* l) {
  __builtin_amdgcn_global_load_lds(
      (const __attribute__((address_space(1))) unsigned int*)g,
      (__attribute__((address_space(3))) unsigned int*)l, 16, 0, 0);
}
__device__ __forceinline__ float rdlane(float v, int l) {
  return __builtin_bit_cast(float,
      __builtin_amdgcn_readlane(__builtin_bit_cast(int, v), l));
}

// ---------------------------------------------------------------------------
// K0: x -> xt2[b][kc][k8][d][8] (bf16, k-slice-major); w1 -> w1t[n][k];
//     logits init; njobs[0..3] zero; featws (16MB) zero for refine atomics.
// ---------------------------------------------------------------------------
__global__ __launch_bounds__(256) void k_prep(
    const float* __restrict__ x, const float* __restrict__ w1,
    const float* __restrict__ b2,
    unsigned short* __restrict__ xt, unsigned short* __restrict__ w1t,
    float* __restrict__ logits, int* __restrict__ njobs,
    float* __restrict__ featws) {
  __shared__ float tileS[64][65];
  __shared__ float tx[64][132];
  int bx = blockIdx.x, tid = threadIdx.x;
  if (bx == 0 && tid < 4) njobs[tid] = 0;
  if (bx < 64) {  // logits init: 16384 floats
    int i = bx * 256 + tid;
    logits[i] = b2[i & 1];
  }
  // zero feat workspace: 2 x 8192 x 256 floats = 1048576 float4
  {
    float4 z = {0.f, 0.f, 0.f, 0.f};
    for (int i = bx * 256 + tid; i < 1048576; i += 304 * 256)
      ((float4*)featws)[i] = z;
  }
  if (bx < 256) {  // x-part: 64 t-rows x 128 d-cols per block
    int b = bx >> 6, kc = (bx >> 1) & 31, dh = bx & 1;
    const float* src = x + ((size_t)b * 2048 + (size_t)kc * 64) * 256 + dh * 128;
#pragma unroll
    for (int p = 0; p < 8; ++p) {
      int idx = p * 256 + tid;
      int row = idx >> 5, f4 = idx & 31;
      *(float4*)&tx[row][f4 * 4] = *(const float4*)&src[(size_t)row * 256 + f4 * 4];
    }
    __syncthreads();
    unsigned short* dst = xt + ((size_t)(b * 32 + kc)) * 16384 + dh * 1024;
#pragma unroll
    for (int p = 0; p < 4; ++p) {
      int idx = p * 256 + tid;
      int d0 = idx & 127, k8 = idx >> 7;
      bf16x8 v;
#pragma unroll
      for (int j = 0; j < 8; ++j) v[j] = (short)f2bf(tx[k8 * 8 + j][d0]);
      *(bf16x8*)&dst[(size_t)k8 * 2048 + d0 * 8] = v;
    }
  } else {  // w1 tiles: k-tiles(12) * n-tiles(4)
    int wt = bx - 256;
    int k6 = wt >> 2, n6 = wt & 3;
    int j = tid & 63, i0 = tid >> 6;
    const float* src = w1 + ((size_t)k6 * 64) * 256 + n6 * 64;
    for (int i = i0; i < 64; i += 4) tileS[i][j] = src[(size_t)i * 256 + j];
    __syncthreads();
    unsigned short* dst = w1t + ((size_t)n6 * 64) * 768 + k6 * 64;
    for (int r = i0; r < 64; r += 4) dst[(size_t)r * 768 + j] = f2bf(tileS[j][r]);
  }
}

// ---------------------------------------------------------------------------
// K1 v4 (unchanged): fetch-once, 2 blocks/CU, linear B layout.
// ---------------------------------------------------------------------------
__global__ __launch_bounds__(512, 4) void k_gemm_rep(
    const float* __restrict__ head, const float* __restrict__ tail,
    const unsigned short* __restrict__ xt,
    float* __restrict__ hrep, float* __restrict__ trep) {
  __shared__ unsigned short As[2][2048];   // [k8][row][8]
  __shared__ unsigned short Bs[2][16384];  // [k8][col][8]
  int bx = blockIdx.x;
  int b = bx >> 7, mt = bx & 127;
  const float* Asrc = ((mt < 64) ? head : tail) +
                      ((size_t)(b * 2048 + (mt & 63) * 32)) * 2048;
  float* Crep = (mt < 64) ? hrep : trep;
  const unsigned short* Bsrc = xt + (size_t)b * 524288;

  int tid = threadIdx.x, lane = tid & 63, w = tid >> 6;
  int rg = w & 1, cg = w >> 1;
  int l4 = lane >> 4, l15 = lane & 15;

  int arow = tid >> 3, ak8 = tid & 7;
  const float* aptr = Asrc + (size_t)arow * 2048 + ak8 * 8;
  int awi = (ak8 * 32 + arow) * 8;

  const unsigned short* bg = Bsrc + tid * 8;

  int aoff[2];
  int boff[2][4];
#pragma unroll
  for (int kh = 0; kh < 2; ++kh) {
    aoff[kh] = ((kh * 4 + l4) * 32 + rg * 16 + l15) * 8;
#pragma unroll
    for (int ct = 0; ct < 4; ++ct)
      boff[kh][ct] = ((kh * 4 + l4) * 256 + cg * 64 + ct * 16 + l15) * 8;
  }

  f32x4 acc[4];
#pragma unroll
  for (int ct = 0; ct < 4; ++ct) acc[ct] = (f32x4){0.f, 0.f, 0.f, 0.f};

  float4 av0, av1;
  auto STAGEB = [&](int buf) {
#pragma unroll
    for (int a = 0; a < 4; ++a)
      async_copy16(bg + (size_t)a * 4096, &Bs[buf][(tid + a * 512) * 8]);
    bg += 16384;
  };
  auto LOADA = [&]() {
    const float4* ap = (const float4*)aptr;
    av0 = ap[0]; av1 = ap[1];
    aptr += 64;
  };
  auto WRITEA = [&](int buf) {
    bf16x8 p;
    p[0] = (short)f2bf(av0.x); p[1] = (short)f2bf(av0.y);
    p[2] = (short)f2bf(av0.z); p[3] = (short)f2bf(av0.w);
    p[4] = (short)f2bf(av1.x); p[5] = (short)f2bf(av1.y);
    p[6] = (short)f2bf(av1.z); p[7] = (short)f2bf(av1.w);
    *(bf16x8*)&As[buf][awi] = p;
  };
  auto MMA = [&](int buf) {
    const unsigned short* A_ = As[buf];
    const unsigned short* B_ = Bs[buf];
#pragma unroll
    for (int kh = 0; kh < 2; ++kh) {
      bf16x8 a0 = *(const bf16x8*)&A_[aoff[kh]];
#pragma unroll
      for (int ct = 0; ct < 4; ++ct) {
        bf16x8 bb = *(const bf16x8*)&B_[boff[kh][ct]];
        acc[ct] = __builtin_amdgcn_mfma_f32_16x16x32_bf16(a0, bb, acc[ct], 0, 0, 0);
      }
    }
  };

  STAGEB(0);
  if (tid < 256) { LOADA(); WRITEA(0); }
  __syncthreads();

  for (int it = 0; it < 32; ++it) {
    int cur = it & 1, nxt = cur ^ 1;
    if (it < 31) {
      STAGEB(nxt);
      if (tid < 256) LOADA();
    }
    MMA(cur);
    if (it < 31 && tid < 256) WRITEA(nxt);
    __syncthreads();
  }

  size_t prow = (size_t)b * 2048 + (size_t)(mt & 63) * 32 + rg * 16 + (l4 << 2);
  int cb = cg * 64 + l15;
#pragma unroll
  for (int ct = 0; ct < 4; ++ct)
#pragma unroll
    for (int i = 0; i < 4; ++i)
      Crep[(prow + i) * 256 + cb + ct * 16] = acc[ct][i];
}

// ---------------------------------------------------------------------------
// K2pre: featbf[p][0:256]=h, [256:512]=t, [512:768]=h*t  (bf16)
// ---------------------------------------------------------------------------
__global__ __launch_bounds__(256) void k_feat(
    const float* __restrict__ hrep, const float* __restrict__ trep,
    unsigned short* __restrict__ featbf) {
  int gid = blockIdx.x * 256 + threadIdx.x;
  int p = gid >> 6, d0 = (gid & 63) * 4;
  float4 h4 = *(const float4*)&hrep[(size_t)p * 256 + d0];
  float4 t4 = *(const float4*)&trep[(size_t)p * 256 + d0];
  ushort4 a, bb, c;
  a.x = f2bf(h4.x); a.y = f2bf(h4.y); a.z = f2bf(h4.z); a.w = f2bf(h4.w);
  bb.x = f2bf(t4.x); bb.y = f2bf(t4.y); bb.z = f2bf(t4.z); bb.w = f2bf(t4.w);
  c.x = f2bf(h4.x * t4.x); c.y = f2bf(h4.y * t4.y);
  c.z = f2bf(h4.z * t4.z); c.w = f2bf(h4.w * t4.w);
  *(ushort4*)&featbf[(size_t)p * 768 + d0] = a;
  *(ushort4*)&featbf[(size_t)p * 768 + 256 + d0] = bb;
  *(ushort4*)&featbf[(size_t)p * 768 + 512 + d0] = c;
}

// ---------------------------------------------------------------------------
// K2: relu(feat @ w1 + b1) @ w2 + b2 -> logits (unchanged)
// ---------------------------------------------------------------------------
__global__ __launch_bounds__(256, 4) void k_gemm_mlp(
    const unsigned short* __restrict__ featb, const unsigned short* __restrict__ w1t,
    const float* __restrict__ b1, const float* __restrict__ w2,
    float* __restrict__ logits) {
  __shared__ unsigned short As[2][4096], Bs[2][4096];
  int bx = blockIdx.x;
  int ntile = bx >> 7;
  int mtile = bx & 127;
  int tid = threadIdx.x, lane = tid & 63, w = tid >> 6;

  const unsigned short* ag[2];
  const unsigned short* bgp[2];
  int dofs[2];
#pragma unroll
  for (int a = 0; a < 2; ++a) {
    int rowofs = a * 8 + (lane >> 3);
    int k8 = (lane & 7) ^ (rowofs & 7);
    ag[a] = featb + (size_t)(mtile * 64 + w * 16 + rowofs) * 768 + k8 * 8;
    bgp[a] = w1t + (size_t)(ntile * 64 + w * 16 + rowofs) * 768 + k8 * 8;
    dofs[a] = (w * 128 + a * 64 + lane) * 8;
  }
  int sw0 = (lane >> 4) ^ (lane & 7);
  int sw1 = (4 + (lane >> 4)) ^ (lane & 7);
  int arowc = (w * 16 + (lane & 15)) * 8;
  int colc[4];
#pragma unroll
  for (int ct = 0; ct < 4; ++ct) colc[ct] = (ct * 16 + (lane & 15)) * 8;

  f32x4 acc[4];
#pragma unroll
  for (int ct = 0; ct < 4; ++ct) acc[ct] = (f32x4){0.f, 0.f, 0.f, 0.f};

#pragma unroll
  for (int a = 0; a < 2; ++a) {
    async_copy16(ag[a], &As[0][dofs[a]]); ag[a] += 64;
    async_copy16(bgp[a], &Bs[0][dofs[a]]); bgp[a] += 64;
  }
  __syncthreads();

  for (int it = 0; it < 12; ++it) {
    int cur = it & 1, nxt = cur ^ 1;
    if (it < 11) {
#pragma unroll
      for (int a = 0; a < 2; ++a) {
        async_copy16(ag[a], &As[nxt][dofs[a]]); ag[a] += 64;
        async_copy16(bgp[a], &Bs[nxt][dofs[a]]); bgp[a] += 64;
      }
    }
    const unsigned short* A_ = As[cur];
    const unsigned short* B_ = Bs[cur];
    bf16x8 a0 = *(const bf16x8*)&A_[(arowc + sw0) * 8];
    bf16x8 a1 = *(const bf16x8*)&A_[(arowc + sw1) * 8];
#pragma unroll
    for (int ct = 0; ct < 4; ++ct) {
      bf16x8 b0 = *(const bf16x8*)&B_[(colc[ct] + sw0) * 8];
      acc[ct] = __builtin_amdgcn_mfma_f32_16x16x32_bf16(a0, b0, acc[ct], 0, 0, 0);
    }
#pragma unroll
    for (int ct = 0; ct < 4; ++ct) {
      bf16x8 b1 = *(const bf16x8*)&B_[(colc[ct] + sw1) * 8];
      acc[ct] = __builtin_amdgcn_mfma_f32_16x16x32_bf16(a1, b1, acc[ct], 0, 0, 0);
    }
    __syncthreads();
  }

  float bv[4], w20[4], w21[4];
#pragma unroll
  for (int ct = 0; ct < 4; ++ct) {
    int col = ntile * 64 + ct * 16 + (lane & 15);
    bv[ct] = b1[col]; w20[ct] = w2[col * 2]; w21[ct] = w2[col * 2 + 1];
  }
#pragma unroll
  for (int i = 0; i < 4; ++i) {
    float s0 = 0.f, s1 = 0.f;
#pragma unroll
    for (int ct = 0; ct < 4; ++ct) {
      float r = fmaxf(acc[ct][i] + bv[ct], 0.f);
      s0 += r * w20[ct]; s1 += r * w21[ct];
    }
#pragma unroll
    for (int off = 1; off < 16; off <<= 1) {
      s0 += __shfl_xor(s0, off); s1 += __shfl_xor(s1, off);
    }
    if ((lane & 15) == 0) {
      int row = mtile * 64 + w * 16 + ((lane >> 4) << 2) + i;
      atomicAdd(&logits[row * 2], s0);
      atomicAdd(&logits[row * 2 + 1], s1);
    }
  }
}

// ---------------------------------------------------------------------------
// K3b: per-mention top-1 + uncertainty set; emit refine jobs BUCKETED BY b
// ---------------------------------------------------------------------------
__global__ void k_select(const float* __restrict__ logits, int* __restrict__ idxv,
                         float* __restrict__ mval, int* __restrict__ cmask,
                         int* __restrict__ njobs, int* __restrict__ jobs) {
  int q = blockIdx.x * 256 + threadIdx.x;
  if (q >= 512) return;
  int base = q * 16;
  float s[16];
#pragma unroll
  for (int i = 0; i < 16; ++i) s[i] = logits[(size_t)(base + i) * 2 + 1];
  float best = s[0]; int bi = 0;
#pragma unroll
  for (int i = 1; i < 16; ++i) if (s[i] > best) { best = s[i]; bi = i; }
  int mask = 0, cnt = 0;
#pragma unroll
  for (int i = 0; i < 16; ++i) if (s[i] > best - TAU) { mask |= 1 << i; ++cnt; }
  idxv[q] = bi; mval[q] = best;
  if (cnt > 1) {
    cmask[q] = mask;
    int bb = q >> 7;   // batch index (code>>11 == q>>7)
    for (int i = 0; i < 16; ++i)
      if ((mask >> i) & 1) {
        int j = atomicAdd(&njobs[bb], 1);
        jobs[bb * 2048 + j] = base + i;
      }
  } else cmask[q] = 0;
}

// ---------------------------------------------------------------------------
// K3c-A: batched fp32 dot phase. Task = (JPB=8 same-b jobs) x (t-chunk 256).
// Flat task index over all b (NO serial-b loop: round-5's parallelism bug).
// Rows in REGISTERS (wave-coalesced load, v_readlane broadcast, zero LDS in
// inner loop); x read coalesced; LDS reduce over 4 t-subgroups; guarded
// atomicAdd into zeroed featH/featT workspace.
// ---------------------------------------------------------------------------
__global__ __launch_bounds__(1024) void k_refine_dot(
    const int* __restrict__ njobs, const int* __restrict__ jobs,
    const float* __restrict__ head, const float* __restrict__ tail,
    const float* __restrict__ x,
    float* __restrict__ featH, float* __restrict__ featT) {
  __shared__ float red[4][16][256];   // 64KB
  __shared__ int scode[8];
  int tid = threadIdx.x, lane = tid & 63, w = tid >> 6;
  int tg = w >> 2, dg = w & 3;        // 4 t-subgroups x 4 d-groups
  int d = dg * 64 + lane;

  for (int gt = blockIdx.x; ; gt += gridDim.x) {
    int rem = gt, b = 0, nj = 0;
    for (; b < 4; ++b) {
      nj = njobs[b];
      int ntb = ((nj + 7) >> 3) * 8;     // groups * TSPLIT(8)
      if (rem < ntb) break;
      rem -= ntb;
    }
    if (b == 4) break;
    int grp = rem >> 3, tc = rem & 7;
    __syncthreads();   // protect scode from previous iteration's readers
    if (tid < 8) scode[tid] = jobs[b * 2048 + min(grp * 8 + tid, nj - 1)];
    __syncthreads();

    int t0 = tc * 256 + tg * 64;
    float vh[8], vt[8];
#pragma unroll
    for (int j = 0; j < 8; ++j) {
      int p = scode[j] & 2047;
      size_t ro = ((size_t)(b * 2048 + p)) * 2048 + t0 + lane;
      vh[j] = head[ro]; vt[j] = tail[ro];
    }
    float ah[8] = {0.f, 0.f, 0.f, 0.f, 0.f, 0.f, 0.f, 0.f};
    float at[8] = {0.f, 0.f, 0.f, 0.f, 0.f, 0.f, 0.f, 0.f};
    const float* xp = x + (size_t)b * 524288 + (size_t)t0 * 256 + d;
#pragma unroll 8
    for (int t = 0; t < 64; ++t) {
      float xv = xp[(size_t)t * 256];
#pragma unroll
      for (int j = 0; j < 8; ++j) {
        ah[j] += rdlane(vh[j], t) * xv;
        at[j] += rdlane(vt[j], t) * xv;
      }
    }
#pragma unroll
    for (int j = 0; j < 8; ++j) {
      red[tg][j][d] = ah[j];
      red[tg][8 + j][d] = at[j];
    }
    __syncthreads();
    if (tid < 256) {
#pragma unroll
      for (int j = 0; j < 16; ++j) {
        float s = red[0][j][tid] + red[1][j][tid] + red[2][j][tid] + red[3][j][tid];
        int jj = j & 7;
        if (grp * 8 + jj < nj) {
          float* dst = (j < 8) ? featH : featT;
          atomicAdd(&dst[(size_t)scode[jj] * 256 + tid], s);
        }
      }
    }
  }
}

// ---------------------------------------------------------------------------
// K3c-B: batched MLP phase. One block per 8-job group (grid-stride, flat
// task index). feat built incl. h*t; hidden pass reads each w1 element once
// per group (8 FMA/elem); guarded refined write.
// ---------------------------------------------------------------------------
__global__ __launch_bounds__(1024) void k_refine_mlp(
    const int* __restrict__ njobs, const int* __restrict__ jobs,
    const float* __restrict__ featH, const float* __restrict__ featT,
    const float* __restrict__ w1, const float* __restrict__ b1,
    const float* __restrict__ w2, const float* __restrict__ b2,
    float* __restrict__ refined) {
  __shared__ float feat8[768][8];     // 24KB
  __shared__ float redm[4][8][256];   // 32KB
  __shared__ float part[8][4];
  __shared__ int scode[8];
  int tid = threadIdx.x;
  int hseg = tid >> 8, d = tid & 255;

  for (int gt = blockIdx.x; ; gt += gridDim.x) {
    int rem = gt, b = 0, nj = 0;
    for (; b < 4; ++b) {
      nj = njobs[b];
      int ntb = (nj + 7) >> 3;
      if (rem < ntb) break;
      rem -= ntb;
    }
    if (b == 4) break;
    int grp = rem;
    __syncthreads();
    if (tid < 8) scode[tid] = jobs[b * 2048 + min(grp * 8 + tid, nj - 1)];
    __syncthreads();
#pragma unroll
    for (int r = 0; r < 2; ++r) {
      int j = hseg * 2 + r;   // 0..7
      float h = featH[(size_t)scode[j] * 256 + d];
      float t = featT[(size_t)scode[j] * 256 + d];
      feat8[d][j] = h; feat8[256 + d][j] = t; feat8[512 + d][j] = h * t;
    }
    __syncthreads();
    float hp[8] = {0.f, 0.f, 0.f, 0.f, 0.f, 0.f, 0.f, 0.f};
    const float* w1c = w1 + (size_t)(hseg * 192) * 256 + d;
#pragma unroll 4
    for (int ii = 0; ii < 192; ++ii) {
      float wv = w1c[(size_t)ii * 256];
      float4 f0 = *(const float4*)&feat8[hseg * 192 + ii][0];
      float4 f1 = *(const float4*)&feat8[hseg * 192 + ii][4];
      hp[0] += f0.x * wv; hp[1] += f0.y * wv; hp[2] += f0.z * wv; hp[3] += f0.w * wv;
      hp[4] += f1.x * wv; hp[5] += f1.y * wv; hp[6] += f1.z * wv; hp[7] += f1.w * wv;
    }
#pragma unroll
    for (int j = 0; j < 8; ++j) redm[hseg][j][d] = hp[j];
    __syncthreads();
    if (tid < 256) {
      float w2v = w2[tid * 2 + 1], b1v = b1[tid];
#pragma unroll
      for (int j = 0; j < 8; ++j) {
        float h = b1v + redm[0][j][tid] + redm[1][j][tid] + redm[2][j][tid] + redm[3][j][tid];
        h = fmaxf(h, 0.f) * w2v;
#pragma unroll
        for (int off = 1; off < 64; off <<= 1) h += __shfl_xor(h, off);
        if ((tid & 63) == 0) part[j][tid >> 6] = h;
      }
    }
    __syncthreads();
    if (tid < 8 && grp * 8 + tid < nj)
      refined[scode[tid]] = part[tid][0] + part[tid][1] + part[tid][2] + part[tid][3] + b2[1];
  }
}

// ---------------------------------------------------------------------------
// K4a: rep_m[q][d] = tail_rep[q*16+argmax][d] * max_val
// ---------------------------------------------------------------------------
__global__ __launch_bounds__(256) void k_repm(
    const int* __restrict__ idxv, const float* __restrict__ mval,
    const int* __restrict__ cmask, const float* __restrict__ refined,
    const float* __restrict__ trep, float* __restrict__ repm) {
  int q = blockIdx.x, d = threadIdx.x;
  int mask = cmask[q]; int bi; float v;
  if (mask) {
    bi = -1; v = -1e30f;
    for (int i = 0; i < 16; ++i)
      if ((mask >> i) & 1) { float s = refined[q * 16 + i]; if (s > v) { v = s; bi = i; } }
  } else { bi = idxv[q]; v = mval[q]; }
  repm[(size_t)q * 256 + d] = trep[((size_t)q * 16 + bi) * 256 + d] * v;
}

// ---------------------------------------------------------------------------
// K4b: out[b][t][d] = x + sum_m cmp[b][m][t] * rep_m[b][m][d]  (512 blocks)
// ---------------------------------------------------------------------------
__global__ __launch_bounds__(256) void k_merge(
    const float* __restrict__ cmp, const float* __restrict__ repm,
    const float* __restrict__ x, float* __restrict__ out) {
  __shared__ float cl[128 * 16];
  int bx = blockIdx.x, b = bx >> 7, t0 = (bx & 127) * 16;
  int tid = threadIdx.x;
#pragma unroll
  for (int it = 0; it < 2; ++it) {
    int f = it * 256 + tid;
    int row = f >> 2, c4 = (f & 3) * 4;
    *(float4*)&cl[row * 16 + c4] =
        *(const float4*)&cmp[((size_t)(b * 128 + row)) * 2048 + t0 + c4];
  }
  __syncthreads();
  float acc[16];
#pragma unroll
  for (int i = 0; i < 16; ++i) acc[i] = 0.f;
  int d = tid;
  for (int m = 0; m < 128; ++m) {
    float rv = repm[(size_t)(b * 128 + m) * 256 + d];
    const float4* c4p = (const float4*)&cl[m * 16];
#pragma unroll
    for (int jj = 0; jj < 4; ++jj) {
      float4 c = c4p[jj];
      acc[jj * 4] += c.x * rv; acc[jj * 4 + 1] += c.y * rv;
      acc[jj * 4 + 2] += c.z * rv; acc[jj * 4 + 3] += c.w * rv;
    }
  }
  const float* xb = x + ((size_t)(b * 2048 + t0)) * 256 + d;
  float* ob = out + ((size_t)(b * 2048 + t0)) * 256 + d;
#pragma unroll
  for (int tt = 0; tt < 16; ++tt) ob[(size_t)tt * 256] = xb[(size_t)tt * 256] + acc[tt];
}

// ---------------------------------------------------------------------------
// K5: masked KLDiv mean loss (single block)
// ---------------------------------------------------------------------------
__global__ __launch_bounds__(1024) void k_loss(
    const float* __restrict__ logits, const float* __restrict__ lab,
    const unsigned char* __restrict__ mask, float* __restrict__ out_loss) {
  __shared__ float rs[1024], rc[1024];
  int tid = threadIdx.x;
  float sum = 0.f, cnt = 0.f;
  for (int p = tid; p < 8192; p += 1024) {
    float l0 = logits[(size_t)p * 2], l1 = logits[(size_t)p * 2 + 1];
    float a0 = lab[(size_t)p * 2], a1 = lab[(size_t)p * 2 + 1];
    float mx = fmaxf(l0, l1);
    float lse = mx + logf(expf(l0 - mx) + expf(l1 - mx));
    float pw = 0.f;
    if (a0 > 0.f) pw += a0 * logf(fmaxf(a0, 1e-38f));
    if (a1 > 0.f) pw += a1 * logf(fmaxf(a1, 1e-38f));
    pw -= a0 * (l0 - lse) + a1 * (l1 - lse);
    if (mask[p]) { sum += pw; cnt += 1.f; }
  }
  rs[tid] = sum; rc[tid] = cnt;
  __syncthreads();
  for (int s = 512; s > 0; s >>= 1) {
    if (tid < s) { rs[tid] += rs[tid + s]; rc[tid] += rc[tid + s]; }
    __syncthreads();
  }
  if (tid == 0) *out_loss = rs[0] / (rc[0] * 2.0f);
}

// ---------------------------------------------------------------------------
extern "C" void kernel_launch(void* const* d_in, const int* in_sizes, int n_in,
                              void* d_out, int out_size, void* d_ws, size_t ws_size,
                              hipStream_t stream) {
  (void)in_sizes; (void)n_in; (void)out_size; (void)ws_size;
  const float* head = (const float*)d_in[0];
  const float* tail = (const float*)d_in[1];
  // d_in[2] = lens (uniform L=16) -- unused
  const float* x = (const float*)d_in[3];
  const float* cmp = (const float*)d_in[4];
  const float* lab = (const float*)d_in[5];
  const unsigned char* lmask = (const unsigned char*)d_in[6];
  const float* w1 = (const float*)d_in[7];
  const float* b1 = (const float*)d_in[8];
  const float* w2 = (const float*)d_in[9];
  const float* b2 = (const float*)d_in[10];
  float* out = (float*)d_out;

  char* ws = (char*)d_ws;
  size_t off = 0;
  auto alloc = [&](size_t bytes) -> void* {
    void* p = ws + off; off += (bytes + 255) & ~(size_t)255; return p;
  };
  unsigned short* xt = (unsigned short*)alloc(4ull * 256 * 2048 * 2);
  unsigned short* w1t = (unsigned short*)alloc(256ull * 768 * 2);
  float* hrep = (float*)alloc(8192ull * 256 * 4);
  float* trep = (float*)alloc(8192ull * 256 * 4);
  unsigned short* featb = (unsigned short*)alloc(8192ull * 768 * 2);
  float* logits = (float*)alloc(8192ull * 2 * 4);
  float* refined = (float*)alloc(8192ull * 4);
  int* idxv = (int*)alloc(512 * 4);
  float* mvalv = (float*)alloc(512 * 4);
  int* cmaskv = (int*)alloc(512 * 4);
  int* njobs = (int*)alloc(256);
  int* jobs = (int*)alloc(4 * 2048 * 4);
  float* repm = (float*)alloc(512ull * 256 * 4);
  float* featH = (float*)alloc(8192ull * 256 * 4);   // contiguous with featT
  float* featT = (float*)alloc(8192ull * 256 * 4);

  k_prep<<<304, 256, 0, stream>>>(x, w1, b2, xt, w1t, logits, njobs, featH);
  k_gemm_rep<<<512, 512, 0, stream>>>(head, tail, xt, hrep, trep);
  k_feat<<<2048, 256, 0, stream>>>(hrep, trep, featb);
  k_gemm_mlp<<<512, 256, 0, stream>>>(featb, w1t, b1, w2, logits);
  k_select<<<2, 256, 0, stream>>>(logits, idxv, mvalv, cmaskv, njobs, jobs);
  k_refine_dot<<<512, 1024, 0, stream>>>(njobs, jobs, head, tail, x, featH, featT);
  k_refine_mlp<<<128, 1024, 0, stream>>>(njobs, jobs, featH, featT, w1, b1, w2, b2, refined);
  k_repm<<<512, 256, 0, stream>>>(idxv, mvalv, cmaskv, refined, trep, repm);
  k_merge<<<512, 256, 0, stream>>>(cmp, repm, x, out);
  k_loss<<<1, 1024, 0, stream>>>(logits, lab, lmask, out + 4ull * 2048 * 256);
}